// Round 1
// baseline (252.337 us; speedup 1.0000x reference)
//
#include <hip/hip_runtime.h>

#define T_GT 64

// ---------------------------------------------------------------------------
// Kernel A: per (b, t) find argmax_p IoU(t, p), first-index tie-break.
// Wave layout: lane = t (64 gt boxes == 64 lanes). Each wave scans a
// contiguous chunk of priors; combine across waves with atomicMax on
// packed (iou_bits << 32) | (0xFFFFFFFF - p)   [iou >= 0 so float bits are
// monotonic as u32; ~p makes ties pick the smallest p, matching np.argmax].
// ---------------------------------------------------------------------------
__global__ void best_prior_kernel(const float* __restrict__ priors,
                                  const float* __restrict__ gt_boxes,
                                  unsigned long long* __restrict__ bp,
                                  int P, int chunks, int chunk_len) {
    const int lane  = threadIdx.x & 63;
    const int wave  = threadIdx.x >> 6;
    const int b     = blockIdx.y;
    const int chunk = blockIdx.x * (blockDim.x >> 6) + wave;
    if (chunk >= chunks) return;

    // gt box for this lane's t (matches ref: boxes1 = gt, already xyxy)
    const float4 gb = ((const float4*)gt_boxes)[b * T_GT + lane];
    const float garea = (gb.z - gb.x) * (gb.w - gb.y);

    int p0 = chunk * chunk_len;
    int p1 = p0 + chunk_len;
    if (p1 > P) p1 = P;

    float best_v = -1.0f;           // any real iou (>=0) beats this
    unsigned int best_p = 0u;
    for (int p = p0; p < p1; ++p) {
        const float4 pr = ((const float4*)priors)[p];   // cx, cy, w, h
        // ref: priors_xyxy = [cxcy - wh/2, cxcy + wh/2]; 0.5f*w == w/2 exactly
        const float px0 = pr.x - 0.5f * pr.z;
        const float py0 = pr.y - 0.5f * pr.w;
        const float px1 = pr.x + 0.5f * pr.z;
        const float py1 = pr.y + 0.5f * pr.w;
        // ref computes area2 from the ROUNDED xyxy coords:
        const float parea = (px1 - px0) * (py1 - py0);
        const float ltx = fmaxf(gb.x, px0);
        const float lty = fmaxf(gb.y, py0);
        const float rbx = fminf(gb.z, px1);
        const float rby = fminf(gb.w, py1);
        const float wx = fmaxf(rbx - ltx, 0.0f);
        const float wy = fmaxf(rby - lty, 0.0f);
        const float inter = wx * wy;
        const float uni = (garea + parea) - inter;   // ref op order
        const float q = inter / uni;                 // IEEE f32 divide
        if (q > best_v) { best_v = q; best_p = (unsigned int)p; }
    }
    if (p0 < p1) {
        const unsigned long long packed =
            ((unsigned long long)__float_as_uint(best_v) << 32) |
            (unsigned long long)(0xFFFFFFFFu - best_p);
        atomicMax(&bp[b * T_GT + lane], packed);
    }
}

// ---------------------------------------------------------------------------
// Kernel B: per (b, p): argmax_t IoU (first-index), apply best-prior override
// (numpy last-wins duplicate semantics), threshold labels, encode loc.
// ---------------------------------------------------------------------------
__global__ void match_kernel(const float* __restrict__ priors,
                             const float* __restrict__ gt_boxes,
                             const int* __restrict__ gt_labels,
                             const unsigned long long* __restrict__ bp,
                             float* __restrict__ out_loc,   // (B, P, 4)
                             float* __restrict__ out_lbl,   // (B, P) as float
                             int P) {
    __shared__ float4       s_box[T_GT];
    __shared__ float        s_area[T_GT];
    __shared__ int          s_lbl[T_GT];
    __shared__ unsigned int s_bp[T_GT];

    const int b   = blockIdx.y;
    const int tid = threadIdx.x;
    if (tid < T_GT) {
        const float4 gb = ((const float4*)gt_boxes)[b * T_GT + tid];
        s_box[tid]  = gb;
        s_area[tid] = (gb.z - gb.x) * (gb.w - gb.y);
        s_lbl[tid]  = gt_labels[b * T_GT + tid];
        s_bp[tid]   = 0xFFFFFFFFu - (unsigned int)(bp[b * T_GT + tid] & 0xFFFFFFFFull);
    }
    __syncthreads();

    const int p = blockIdx.x * blockDim.x + tid;
    if (p >= P) return;

    const float4 pr = ((const float4*)priors)[p];   // cx, cy, w, h
    const float px0 = pr.x - 0.5f * pr.z;
    const float py0 = pr.y - 0.5f * pr.w;
    const float px1 = pr.x + 0.5f * pr.z;
    const float py1 = pr.y + 0.5f * pr.w;
    const float parea = (px1 - px0) * (py1 - py0);

    float best_v = -1.0f;
    int   best_t = 0;
    for (int t = 0; t < T_GT; ++t) {
        const float4 gb = s_box[t];
        const float ltx = fmaxf(gb.x, px0);
        const float lty = fmaxf(gb.y, py0);
        const float rbx = fminf(gb.z, px1);
        const float rby = fminf(gb.w, py1);
        const float wx = fmaxf(rbx - ltx, 0.0f);
        const float wy = fmaxf(rby - lty, 0.0f);
        const float inter = wx * wy;
        const float uni = (s_area[t] + parea) - inter;
        const float q = inter / uni;                 // IEEE f32 divide
        if (q > best_v) { best_v = q; best_t = t; }  // strict > keeps first t
    }

    // matches[best_prior] = arange(T): ascending scan, last t wins on dups
    int  match  = best_t;
    bool forced = false;
    for (int t = 0; t < T_GT; ++t) {
        if (s_bp[t] == (unsigned int)p) { match = t; forced = true; }
    }

    int lbl = s_lbl[match];
    if (!forced && best_v < 0.5f) lbl = 0;   // forced => matched_val = 2.0

    const float4 mb  = s_box[match];
    const float  bcx = (mb.x + mb.z) * 0.5f;   // (x0+x1)/2, /2 exact
    const float  bcy = (mb.y + mb.w) * 0.5f;
    const float  bw  = mb.z - mb.x;
    const float  bh  = mb.w - mb.y;

    float4 loc;
    loc.x = (bcx - pr.x) / (0.1f * pr.z);
    loc.y = (bcy - pr.y) / (0.1f * pr.w);
    loc.z = logf(bw / pr.z) / 0.2f;
    loc.w = logf(bh / pr.w) / 0.2f;

    ((float4*)out_loc)[(size_t)b * P + p] = loc;
    out_lbl[(size_t)b * P + p] = (float)lbl;
}

extern "C" void kernel_launch(void* const* d_in, const int* in_sizes, int n_in,
                              void* d_out, int out_size, void* d_ws, size_t ws_size,
                              hipStream_t stream) {
    const float* priors    = (const float*)d_in[0];   // (P, 4) f32
    const float* gt_boxes  = (const float*)d_in[1];   // (B, T, 4) f32
    const int*   gt_labels = (const int*)d_in[2];     // (B, T) i32

    const int P = in_sizes[0] / 4;
    const int B = in_sizes[2] / T_GT;

    float* out_loc = (float*)d_out;                       // B*P*4 floats
    float* out_lbl = out_loc + (size_t)B * P * 4;         // B*P floats

    unsigned long long* bp = (unsigned long long*)d_ws;   // B*T packed u64
    hipMemsetAsync(d_ws, 0, (size_t)B * T_GT * sizeof(unsigned long long), stream);

    // Kernel A: 64 blocks x 4 waves = 256 chunks per image
    const int chunks = 256;
    const int chunk_len = (P + chunks - 1) / chunks;
    dim3 gA(chunks / 4, B);
    best_prior_kernel<<<gA, 256, 0, stream>>>(priors, gt_boxes, bp, P, chunks, chunk_len);

    dim3 gB((P + 255) / 256, B);
    match_kernel<<<gB, 256, 0, stream>>>(priors, gt_boxes, gt_labels, bp,
                                         out_loc, out_lbl, P);
}

// Round 2
// 237.027 us; speedup vs baseline: 1.0646x; 1.0646x over previous
//
#include <hip/hip_runtime.h>

#define T_GT 64
#define GX 32
#define NBINS (GX * GX)

typedef unsigned int u32;
typedef unsigned long long u64;

__device__ __forceinline__ int bin_of(float v) {
    int i = (int)floorf(v * (float)GX);
    return min(max(i, 0), GX - 1);
}

// ---------------------------------------------------------------------------
// Bin-build pipeline: max w/h reduce -> histogram -> prefix scan -> scatter
// ---------------------------------------------------------------------------
__global__ void maxwh_kernel(const float4* __restrict__ priors, u32* __restrict__ maxwh, int P) {
    int idx = blockIdx.x * blockDim.x + threadIdx.x;
    int stride = gridDim.x * blockDim.x;
    float mw = 0.0f, mh = 0.0f;
    for (int p = idx; p < P; p += stride) {
        float4 pr = priors[p];
        mw = fmaxf(mw, pr.z);
        mh = fmaxf(mh, pr.w);
    }
    // wave reduce (positive floats: u32 bit order == float order)
    for (int s = 1; s < 64; s <<= 1) {
        mw = fmaxf(mw, __shfl_xor(mw, s));
        mh = fmaxf(mh, __shfl_xor(mh, s));
    }
    if ((threadIdx.x & 63) == 0) {
        atomicMax(&maxwh[0], __float_as_uint(mw));
        atomicMax(&maxwh[1], __float_as_uint(mh));
    }
}

__global__ void hist_kernel(const float4* __restrict__ priors, u32* __restrict__ counts, int P) {
    int p = blockIdx.x * blockDim.x + threadIdx.x;
    if (p >= P) return;
    float4 pr = priors[p];
    int bin = bin_of(pr.y) * GX + bin_of(pr.x);
    atomicAdd(&counts[bin], 1u);
}

// single block, NBINS threads. counts arrives in `cursor`; writes exclusive
// prefix into both start[] (persistent) and cursor[] (scatter working copy).
__global__ void scan_kernel(u32* __restrict__ start, u32* __restrict__ cursor) {
    __shared__ u32 buf[NBINS];
    int tid = threadIdx.x;
    u32 c = cursor[tid];
    buf[tid] = c;
    __syncthreads();
    for (int off = 1; off < NBINS; off <<= 1) {
        u32 v = (tid >= off) ? buf[tid - off] : 0u;
        __syncthreads();
        buf[tid] += v;
        __syncthreads();
    }
    u32 excl = buf[tid] - c;
    start[tid] = excl;
    cursor[tid] = excl;
    if (tid == NBINS - 1) start[NBINS] = buf[NBINS - 1];
}

__global__ void scatter_kernel(const float4* __restrict__ priors, u32* __restrict__ cursor,
                               float4* __restrict__ sorted, int* __restrict__ sidx, int P) {
    int p = blockIdx.x * blockDim.x + threadIdx.x;
    if (p >= P) return;
    float4 pr = priors[p];
    int bin = bin_of(pr.y) * GX + bin_of(pr.x);
    u32 pos = atomicAdd(&cursor[bin], 1u);
    sorted[pos] = pr;
    sidx[pos] = p;
}

// ---------------------------------------------------------------------------
// Binned kernel A: 4 waves cooperate per (b,t); each scans a stripe of the
// candidate bins. Non-candidate priors have inter==0 -> q==+0.0f exactly,
// covered by init best=(q=0.0f, p=0). Packed (q_bits<<32)|~p u64-max gives
// exactly numpy's first-index-among-rounded-max, order-independent.
// ---------------------------------------------------------------------------
__global__ void best_prior_binned(const float* __restrict__ gt_boxes,
                                  const float4* __restrict__ sorted,
                                  const int* __restrict__ sidx,
                                  const u32* __restrict__ start,
                                  const u32* __restrict__ maxwh,
                                  u64* __restrict__ bp) {
    const int lane = threadIdx.x & 63;
    const int gw   = (blockIdx.x * blockDim.x + threadIdx.x) >> 6;  // global wave
    const int sub  = gw & 3;       // stripe 0..3
    const int wt   = gw >> 2;      // b*T_GT + t
    const float4 gb = ((const float4*)gt_boxes)[wt];
    const float garea = (gb.z - gb.x) * (gb.w - gb.y);
    const float ex = 0.5f * __uint_as_float(maxwh[0]) + 1e-5f;
    const float ey = 0.5f * __uint_as_float(maxwh[1]) + 1e-5f;
    const int x0 = bin_of(gb.x - ex), x1 = bin_of(gb.z + ex);
    const int y0 = bin_of(gb.y - ey), y1 = bin_of(gb.w + ey);

    u64 best = 0xFFFFFFFFull;   // (q=+0.0f bits)<<32 | ~0 -> prior index 0

    for (int y = y0; y <= y1; ++y) {
        const u32 s0 = start[y * GX + x0];
        const u32 s1 = start[y * GX + x1 + 1];     // contiguous segment in x
        for (u32 i = s0 + (u32)(sub * 64 + lane); i < s1; i += 256u) {
            const float4 pr = sorted[i];
            const float px0 = pr.x - 0.5f * pr.z;
            const float py0 = pr.y - 0.5f * pr.w;
            const float px1 = pr.x + 0.5f * pr.z;
            const float py1 = pr.y + 0.5f * pr.w;
            const float parea = (px1 - px0) * (py1 - py0);
            const float ltx = fmaxf(gb.x, px0);
            const float lty = fmaxf(gb.y, py0);
            const float rbx = fminf(gb.z, px1);
            const float rby = fminf(gb.w, py1);
            const float wx = fmaxf(rbx - ltx, 0.0f);
            const float wy = fmaxf(rby - lty, 0.0f);
            const float inter = wx * wy;
            const float uni = (garea + parea) - inter;
            const float q = inter / uni;            // IEEE f32 divide
            const u64 pk = ((u64)__float_as_uint(q) << 32)
                         | (u64)(0xFFFFFFFFu - (u32)sidx[i]);
            if (pk > best) best = pk;
        }
    }
    for (int s = 1; s < 64; s <<= 1) {
        u64 o = __shfl_xor(best, s);
        if (o > best) best = o;
    }
    if (lane == 0) atomicMax(&bp[wt], best);
}

// ---------------------------------------------------------------------------
// Fallback kernel A (round-1): full chunked scan, used if ws too small.
// ---------------------------------------------------------------------------
__global__ void best_prior_kernel(const float* __restrict__ priors,
                                  const float* __restrict__ gt_boxes,
                                  u64* __restrict__ bp,
                                  int P, int chunks, int chunk_len) {
    const int lane  = threadIdx.x & 63;
    const int wave  = threadIdx.x >> 6;
    const int b     = blockIdx.y;
    const int chunk = blockIdx.x * (blockDim.x >> 6) + wave;
    if (chunk >= chunks) return;
    const float4 gb = ((const float4*)gt_boxes)[b * T_GT + lane];
    const float garea = (gb.z - gb.x) * (gb.w - gb.y);
    int p0 = chunk * chunk_len;
    int p1 = p0 + chunk_len;
    if (p1 > P) p1 = P;
    float best_v = -1.0f;
    u32 best_p = 0u;
    for (int p = p0; p < p1; ++p) {
        const float4 pr = ((const float4*)priors)[p];
        const float px0 = pr.x - 0.5f * pr.z;
        const float py0 = pr.y - 0.5f * pr.w;
        const float px1 = pr.x + 0.5f * pr.z;
        const float py1 = pr.y + 0.5f * pr.w;
        const float parea = (px1 - px0) * (py1 - py0);
        const float ltx = fmaxf(gb.x, px0);
        const float lty = fmaxf(gb.y, py0);
        const float rbx = fminf(gb.z, px1);
        const float rby = fminf(gb.w, py1);
        const float wx = fmaxf(rbx - ltx, 0.0f);
        const float wy = fmaxf(rby - lty, 0.0f);
        const float inter = wx * wy;
        const float uni = (garea + parea) - inter;
        const float q = inter / uni;
        if (q > best_v) { best_v = q; best_p = (u32)p; }
    }
    if (p0 < p1) {
        const u64 packed = ((u64)__float_as_uint(best_v) << 32)
                         | (u64)(0xFFFFFFFFu - best_p);
        atomicMax(&bp[b * T_GT + lane], packed);
    }
}

// ---------------------------------------------------------------------------
// Kernel B: per (b,p) argmax_t IoU (first-index), threshold, encode loc.
// Overrides handled later by fixup_kernel.
// ---------------------------------------------------------------------------
__global__ void match_kernel(const float* __restrict__ priors,
                             const float* __restrict__ gt_boxes,
                             const int* __restrict__ gt_labels,
                             float* __restrict__ out_loc,   // (B, P, 4)
                             float* __restrict__ out_lbl,   // (B, P) as float
                             int P) {
    __shared__ float4 s_box[T_GT];
    __shared__ float  s_area[T_GT];
    __shared__ int    s_lbl[T_GT];

    const int b   = blockIdx.y;
    const int tid = threadIdx.x;
    if (tid < T_GT) {
        const float4 gb = ((const float4*)gt_boxes)[b * T_GT + tid];
        s_box[tid]  = gb;
        s_area[tid] = (gb.z - gb.x) * (gb.w - gb.y);
        s_lbl[tid]  = gt_labels[b * T_GT + tid];
    }
    __syncthreads();

    const int p = blockIdx.x * blockDim.x + tid;
    if (p >= P) return;

    const float4 pr = ((const float4*)priors)[p];
    const float px0 = pr.x - 0.5f * pr.z;
    const float py0 = pr.y - 0.5f * pr.w;
    const float px1 = pr.x + 0.5f * pr.z;
    const float py1 = pr.y + 0.5f * pr.w;
    const float parea = (px1 - px0) * (py1 - py0);

    float best_v = -1.0f;
    int   best_t = 0;
    #pragma unroll 8
    for (int t = 0; t < T_GT; ++t) {
        const float4 gb = s_box[t];
        const float ltx = fmaxf(gb.x, px0);
        const float lty = fmaxf(gb.y, py0);
        const float rbx = fminf(gb.z, px1);
        const float rby = fminf(gb.w, py1);
        const float wx = fmaxf(rbx - ltx, 0.0f);
        const float wy = fmaxf(rby - lty, 0.0f);
        const float inter = wx * wy;
        const float uni = (s_area[t] + parea) - inter;
        const float q = inter / uni;                 // IEEE f32 divide
        if (q > best_v) { best_v = q; best_t = t; }  // strict > keeps first t
    }

    int lbl = (best_v < 0.5f) ? 0 : s_lbl[best_t];

    const float4 mb  = s_box[best_t];
    const float  bcx = (mb.x + mb.z) * 0.5f;
    const float  bcy = (mb.y + mb.w) * 0.5f;
    const float  bw  = mb.z - mb.x;
    const float  bh  = mb.w - mb.y;

    float4 loc;
    loc.x = (bcx - pr.x) / (0.1f * pr.z);
    loc.y = (bcy - pr.y) / (0.1f * pr.w);
    loc.z = logf(bw / pr.z) / 0.2f;
    loc.w = logf(bh / pr.w) / 0.2f;

    ((float4*)out_loc)[(size_t)b * P + p] = loc;
    out_lbl[(size_t)b * P + p] = (float)lbl;
}

// ---------------------------------------------------------------------------
// Kernel C: apply matches[best_prior[t]] = t override (numpy last-wins on
// duplicates; matched_val=2.0 so no threshold). One block per image, 64 thr.
// ---------------------------------------------------------------------------
__global__ void fixup_kernel(const float* __restrict__ priors,
                             const float* __restrict__ gt_boxes,
                             const int* __restrict__ gt_labels,
                             const u64* __restrict__ bp,
                             float* __restrict__ out_loc,
                             float* __restrict__ out_lbl,
                             int P) {
    __shared__ u32 s_p[T_GT];
    const int b = blockIdx.x;
    const int t = threadIdx.x;
    const u32 p = 0xFFFFFFFFu - (u32)(bp[b * T_GT + t] & 0xFFFFFFFFull);
    s_p[t] = p;
    __syncthreads();
    for (int u = t + 1; u < T_GT; ++u)
        if (s_p[u] == p) return;      // a later t overrides this prior

    const float4 pr = ((const float4*)priors)[p];
    const float4 mb = ((const float4*)gt_boxes)[b * T_GT + t];
    const float  bcx = (mb.x + mb.z) * 0.5f;
    const float  bcy = (mb.y + mb.w) * 0.5f;
    const float  bw  = mb.z - mb.x;
    const float  bh  = mb.w - mb.y;

    float4 loc;
    loc.x = (bcx - pr.x) / (0.1f * pr.z);
    loc.y = (bcy - pr.y) / (0.1f * pr.w);
    loc.z = logf(bw / pr.z) / 0.2f;
    loc.w = logf(bh / pr.w) / 0.2f;

    ((float4*)out_loc)[(size_t)b * P + p] = loc;
    out_lbl[(size_t)b * P + p] = (float)gt_labels[b * T_GT + t];
}

extern "C" void kernel_launch(void* const* d_in, const int* in_sizes, int n_in,
                              void* d_out, int out_size, void* d_ws, size_t ws_size,
                              hipStream_t stream) {
    const float* priors    = (const float*)d_in[0];   // (P, 4) f32
    const float* gt_boxes  = (const float*)d_in[1];   // (B, T, 4) f32
    const int*   gt_labels = (const int*)d_in[2];     // (B, T) i32

    const int P = in_sizes[0] / 4;
    const int B = in_sizes[2] / T_GT;

    float* out_loc = (float*)d_out;
    float* out_lbl = out_loc + (size_t)B * P * 4;

    // workspace layout
    char* ws = (char*)d_ws;
    const size_t bp_bytes = (size_t)B * T_GT * sizeof(u64);
    u64* bp     = (u64*)ws;
    u32* maxwh  = (u32*)(ws + bp_bytes);                 // 2 u32
    u32* start  = maxwh + 2;                             // NBINS+1 u32
    u32* cursor = start + NBINS + 1;                     // NBINS u32
    int* sidx   = (int*)(cursor + NBINS);                // P int
    size_t sorted_off = ((bp_bytes + (2 + NBINS + 1 + NBINS) * 4 + (size_t)P * 4) + 15) & ~(size_t)15;
    float4* sorted = (float4*)(ws + sorted_off);
    const size_t need = sorted_off + (size_t)P * sizeof(float4);

    hipMemsetAsync(bp, 0, bp_bytes, stream);

    if (ws_size >= need) {
        hipMemsetAsync(maxwh, 0, 2 * sizeof(u32), stream);
        hipMemsetAsync(cursor, 0, NBINS * sizeof(u32), stream);

        maxwh_kernel<<<64, 256, 0, stream>>>((const float4*)priors, maxwh, P);
        hist_kernel<<<(P + 255) / 256, 256, 0, stream>>>((const float4*)priors, cursor, P);
        scan_kernel<<<1, NBINS, 0, stream>>>(start, cursor);
        scatter_kernel<<<(P + 255) / 256, 256, 0, stream>>>((const float4*)priors, cursor,
                                                            sorted, sidx, P);
        // 4 waves per (b,t): B*T_GT*4 waves / 4 waves-per-block = B*T_GT blocks
        best_prior_binned<<<B * T_GT, 256, 0, stream>>>(gt_boxes, sorted, sidx,
                                                        start, maxwh, bp);
    } else {
        const int chunks = 512;
        const int chunk_len = (P + chunks - 1) / chunks;
        dim3 gA(chunks / 4, B);
        best_prior_kernel<<<gA, 256, 0, stream>>>(priors, gt_boxes, bp, P, chunks, chunk_len);
    }

    dim3 gB((P + 255) / 256, B);
    match_kernel<<<gB, 256, 0, stream>>>(priors, gt_boxes, gt_labels,
                                         out_loc, out_lbl, P);
    fixup_kernel<<<B, T_GT, 0, stream>>>(priors, gt_boxes, gt_labels, bp,
                                         out_loc, out_lbl, P);
}